// Round 2
// baseline (194.240 us; speedup 1.0000x reference)
//
#include <hip/hip_runtime.h>
#include <hip/hip_bf16.h>

// Problem constants (fixed by setup_inputs)
constexpr int B  = 2;
constexpr int C  = 256;       // channels per level
constexpr int H0 = 100, W0 = 152;
constexpr int H1 = 50,  W1 = 76;
constexpr int H2 = 25,  W2 = 38;
constexpr int N  = 128;       // rois per batch
constexpr int K  = B * N;     // 256 rois
constexpr int CT = 3 * C;     // 768 fused channels
constexpr int OUTS = 7;       // output grid

#define DEV __device__ __forceinline__

template <typename T> DEV float ldf(const T* p) { return *p; }
template <> DEV float ldf<__hip_bfloat16>(const __hip_bfloat16* p) { return __bfloat162float(*p); }
template <typename T> DEV void stf(T* p, float v) { *p = v; }
template <> DEV void stf<__hip_bfloat16>(__hip_bfloat16* p, float v) { *p = __float2bfloat16(v); }

// ---------------------------------------------------------------------------
// Kernel 1: fused upsample + concat + NCHW->BHWC transpose.
// Block = (b, y, tile) where tile in [0,12): level = tile>>2, 64-channel slice.
// LDS tile [64][153] (pad -> stride 153, 153%32=25, gcd(25,32)=1: conflict-free).
// Load phase: lanes sweep x (coalesced global reads), write phase: lanes sweep c
// (contiguous BHWC writes).
// ---------------------------------------------------------------------------
template <typename T>
__global__ __launch_bounds__(256) void fuse_kernel(
    const float* __restrict__ x0, const float* __restrict__ x1,
    const float* __restrict__ x2, T* __restrict__ feat) {
  __shared__ float lds[64][153];
  const int blk  = blockIdx.x;
  const int tile = blk % 12;
  const int by   = blk / 12;
  const int y    = by % H0;
  const int b    = by / H0;
  const int t    = threadIdx.x;
  const int level = tile >> 2;          // 0: x0 copy, 1: up(x1), 2: up(x2)
  const int c0l   = (tile & 3) * 64;    // channel base within level

  if (level == 0) {
    for (int i = 0; i < 38; ++i) {
      const int lin = i * 256 + t;
      const int cl = lin / 152, x = lin % 152;
      lds[cl][x] = x0[(((size_t)b * C + (c0l + cl)) * H0 + y) * W0 + x];
    }
  } else if (level == 1) {
    // 2x upsample of x1: src = (dst+0.5)*0.5 - 0.5, edge-clamped
    float fy = fminf(fmaxf(y * 0.5f - 0.25f, 0.f), (float)(H1 - 1));
    int   y0i = (int)floorf(fy);
    float ly  = fy - (float)y0i;
    int   y1i = min(y0i + 1, H1 - 1);
    for (int i = 0; i < 38; ++i) {
      const int lin = i * 256 + t;
      const int cl = lin / 152, x = lin % 152;
      float fx = fminf(fmaxf(x * 0.5f - 0.25f, 0.f), (float)(W1 - 1));
      int   x0i = (int)floorf(fx);
      float lx  = fx - (float)x0i;
      int   x1i = min(x0i + 1, W1 - 1);
      const float* base = x1 + ((size_t)b * C + (c0l + cl)) * (H1 * W1);
      float a = base[y0i * W1 + x0i], bb = base[y0i * W1 + x1i];
      float c = base[y1i * W1 + x0i], d  = base[y1i * W1 + x1i];
      lds[cl][x] = (1.f - ly) * (a + lx * (bb - a)) + ly * (c + lx * (d - c));
    }
  } else {
    // 4x upsample of x2: src = (dst+0.5)*0.25 - 0.5, edge-clamped
    float fy = fminf(fmaxf((y + 0.5f) * 0.25f - 0.5f, 0.f), (float)(H2 - 1));
    int   y0i = (int)floorf(fy);
    float ly  = fy - (float)y0i;
    int   y1i = min(y0i + 1, H2 - 1);
    for (int i = 0; i < 38; ++i) {
      const int lin = i * 256 + t;
      const int cl = lin / 152, x = lin % 152;
      float fx = fminf(fmaxf((x + 0.5f) * 0.25f - 0.5f, 0.f), (float)(W2 - 1));
      int   x0i = (int)floorf(fx);
      float lx  = fx - (float)x0i;
      int   x1i = min(x0i + 1, W2 - 1);
      const float* base = x2 + ((size_t)b * C + (c0l + cl)) * (H2 * W2);
      float a = base[y0i * W2 + x0i], bb = base[y0i * W2 + x1i];
      float c = base[y1i * W2 + x0i], d  = base[y1i * W2 + x1i];
      lds[cl][x] = (1.f - ly) * (a + lx * (bb - a)) + ly * (c + lx * (d - c));
    }
  }
  __syncthreads();
  const int cg = tile * 64;  // global fused-channel base (= level*256 + c0l)
  for (int i = 0; i < 38; ++i) {
    const int lin = i * 256 + t;
    const int x = lin >> 6, cl = lin & 63;
    stf(&feat[(((size_t)b * H0 + y) * W0 + x) * CT + cg + cl], lds[cl][x]);
  }
}

// ---------------------------------------------------------------------------
// Kernel 2: RoIAlign from BHWC feat. Block = (k, ph); 256 threads = channel
// lanes (each owns c, c+256, c+512). 7 pw x 2x2 samples x 4 bilinear corners;
// weights fold validity mask and the 1/4 sample mean. LDS staging for the
// [c][pw] -> [c*49 + ph*7 + pw] output transpose.
// ---------------------------------------------------------------------------
template <typename T>
__global__ __launch_bounds__(256) void roi_kernel(
    const T* __restrict__ feat, const float* __restrict__ boxes,
    const float* __restrict__ ratio, const float* __restrict__ offset,
    const float* __restrict__ shape, float* __restrict__ out) {
  __shared__ float lds[CT * OUTS];
  const int blk = blockIdx.x;
  const int ph  = blk % OUTS;
  const int k   = blk / OUTS;
  const int b   = k >> 7;      // N = 128
  const int t   = threadIdx.x;

  // scale factors (batch 0, per reference)
  const float padded_h = floorf(shape[0] * ratio[0] + 2.f * offset[0]);
  const float padded_w = floorf(shape[1] * ratio[1] + 2.f * offset[1]);
  const float sx = (float)W0 / padded_w;
  const float sy = (float)H0 / padded_h;
  // per-batch roi transform
  const float rHb = ratio[b * 2 + 0], rWb = ratio[b * 2 + 1];
  const float topb = offset[b * 2 + 0], leftb = offset[b * 2 + 1];
  const float* bx = boxes + (size_t)k * 4;
  const float x1s = (bx[0] * rWb + leftb) * sx;
  const float y1s = (bx[1] * rHb + topb) * sy;
  const float x2s = (bx[2] * rWb + leftb) * sx;
  const float y2s = (bx[3] * rHb + topb) * sy;
  const float bw = fmaxf(x2s - x1s, 1.f) / OUTS;
  const float bh = fmaxf(y2s - y1s, 1.f) / OUTS;

  // y-side sample data (2 iy values for this ph)
  float wy[2][2]; int yidx[2][2]; bool vy[2];
  for (int iy = 0; iy < 2; ++iy) {
    const float Y = y1s + (ph + iy * 0.5f + 0.25f) * bh;
    vy[iy] = (Y >= -1.f) && (Y <= (float)H0);
    const float Yc = fminf(fmaxf(Y, 0.f), (float)(H0 - 1));
    const float y0f = floorf(Yc);
    const float ly = Yc - y0f;
    const int y0i = (int)y0f;
    yidx[iy][0] = y0i;
    yidx[iy][1] = min(y0i + 1, H0 - 1);
    wy[iy][0] = 1.f - ly;
    wy[iy][1] = ly;
  }

  for (int pw = 0; pw < OUTS; ++pw) {
    float acc0 = 0.f, acc1 = 0.f, acc2 = 0.f;
    for (int ix = 0; ix < 2; ++ix) {
      const float X = x1s + (pw + ix * 0.5f + 0.25f) * bw;
      const bool vx = (X >= -1.f) && (X <= (float)W0);
      const float Xc = fminf(fmaxf(X, 0.f), (float)(W0 - 1));
      const float x0f = floorf(Xc);
      const float lx = Xc - x0f;
      const int x0i = (int)x0f;
      const int xidx[2] = {x0i, min(x0i + 1, W0 - 1)};
      const float wx[2] = {1.f - lx, lx};
      for (int iy = 0; iy < 2; ++iy) {
        const float vscale = (vx && vy[iy]) ? 0.25f : 0.f;
        #pragma unroll
        for (int cy = 0; cy < 2; ++cy) {
          #pragma unroll
          for (int cx = 0; cx < 2; ++cx) {
            const float w = wy[iy][cy] * wx[cx] * vscale;
            const T* p =
                feat + (((size_t)b * H0 + yidx[iy][cy]) * W0 + xidx[cx]) * CT + t;
            acc0 += w * ldf(p);
            acc1 += w * ldf(p + 256);
            acc2 += w * ldf(p + 512);
          }
        }
      }
    }
    lds[(0 * 256 + t) * OUTS + pw] = acc0;
    lds[(1 * 256 + t) * OUTS + pw] = acc1;
    lds[(2 * 256 + t) * OUTS + pw] = acc2;
  }
  __syncthreads();
  // write out[k, c, ph, pw]; 768*7 = 5376 = 21*256 elements
  for (int i = 0; i < 21; ++i) {
    const int idx = i * 256 + t;
    const int c = idx / OUTS, pw = idx % OUTS;
    out[(size_t)k * (CT * 49) + (size_t)c * 49 + ph * OUTS + pw] = lds[idx];
  }
}

extern "C" void kernel_launch(void* const* d_in, const int* in_sizes, int n_in,
                              void* d_out, int out_size, void* d_ws, size_t ws_size,
                              hipStream_t stream) {
  const float* x0     = (const float*)d_in[0];
  const float* x1     = (const float*)d_in[1];
  const float* x2     = (const float*)d_in[2];
  const float* boxes  = (const float*)d_in[3];
  const float* ratio  = (const float*)d_in[4];
  const float* offset = (const float*)d_in[5];
  const float* shape  = (const float*)d_in[6];
  float* out = (float*)d_out;

  const size_t feat_elems = (size_t)B * H0 * W0 * CT;  // 23,347,200
  const dim3 g1(B * H0 * 12), blk(256);
  const dim3 g2(K * OUTS);

  if (ws_size >= feat_elems * sizeof(float)) {
    float* feat = (float*)d_ws;
    fuse_kernel<float><<<g1, blk, 0, stream>>>(x0, x1, x2, feat);
    roi_kernel<float><<<g2, blk, 0, stream>>>(feat, boxes, ratio, offset, shape, out);
  } else {
    __hip_bfloat16* feat = (__hip_bfloat16*)d_ws;
    fuse_kernel<__hip_bfloat16><<<g1, blk, 0, stream>>>(x0, x1, x2, feat);
    roi_kernel<__hip_bfloat16><<<g2, blk, 0, stream>>>(feat, boxes, ratio, offset, shape, out);
  }
}

// Round 3
// 167.451 us; speedup vs baseline: 1.1600x; 1.1600x over previous
//
#include <hip/hip_runtime.h>
#include <hip/hip_bf16.h>

// Problem constants (fixed by setup_inputs)
constexpr int B  = 2;
constexpr int C  = 256;       // channels per level
constexpr int H0 = 100, W0 = 152;
constexpr int H1 = 50,  W1 = 76;
constexpr int H2 = 25,  W2 = 38;
constexpr int N  = 128;       // rois per batch
constexpr int K  = B * N;     // 256 rois
constexpr int CT = 3 * C;     // 768 fused channels
constexpr int OUTS = 7;       // output grid

#define DEV __device__ __forceinline__

template <typename T> DEV float ldf(const T* p) { return *p; }
template <> DEV float ldf<__hip_bfloat16>(const __hip_bfloat16* p) { return __bfloat162float(*p); }
template <typename T> DEV void stf(T* p, float v) { *p = v; }
template <> DEV void stf<__hip_bfloat16>(__hip_bfloat16* p, float v) { *p = __float2bfloat16(v); }

// 4-wide packed store (16B for float, 8B for bf16)
template <typename T> DEV void st4(T* p, float a, float b, float c, float d);
template <> DEV void st4<float>(float* p, float a, float b, float c, float d) {
  *reinterpret_cast<float4*>(p) = make_float4(a, b, c, d);
}
template <> DEV void st4<__hip_bfloat16>(__hip_bfloat16* p, float a, float b, float c, float d) {
  union { __hip_bfloat16 h[4]; uint2 u; } pk;
  pk.h[0] = __float2bfloat16(a); pk.h[1] = __float2bfloat16(b);
  pk.h[2] = __float2bfloat16(c); pk.h[3] = __float2bfloat16(d);
  *reinterpret_cast<uint2*>(p) = pk.u;
}

// ---------------------------------------------------------------------------
// Kernel 1: fused upsample + concat + NCHW->BHWC transpose.
// Block = (b, y, tile); tile in [0,12): level = tile>>2, 64-channel slice.
// LDS tile [64][153] (153%32=25, gcd(25,32)=1: conflict-free load phase;
// write phase 4ch/lane -> exactly 2 lanes/bank = free).
// Write phase stores 4 packed channels per lane (8B bf16 / 16B f32).
// ---------------------------------------------------------------------------
template <typename T>
__global__ __launch_bounds__(256) void fuse_kernel(
    const float* __restrict__ x0, const float* __restrict__ x1,
    const float* __restrict__ x2, T* __restrict__ feat) {
  __shared__ float lds[64][153];
  const int blk  = blockIdx.x;
  const int tile = blk % 12;
  const int by   = blk / 12;
  const int y    = by % H0;
  const int b    = by / H0;
  const int t    = threadIdx.x;
  const int level = tile >> 2;          // 0: x0 copy, 1: up(x1), 2: up(x2)
  const int c0l   = (tile & 3) * 64;    // channel base within level

  if (level == 0) {
    for (int i = 0; i < 38; ++i) {
      const int lin = i * 256 + t;
      const int cl = lin / 152, x = lin % 152;
      lds[cl][x] = x0[(((size_t)b * C + (c0l + cl)) * H0 + y) * W0 + x];
    }
  } else if (level == 1) {
    // 2x upsample of x1: src = (dst+0.5)*0.5 - 0.5, edge-clamped
    float fy = fminf(fmaxf(y * 0.5f - 0.25f, 0.f), (float)(H1 - 1));
    int   y0i = (int)floorf(fy);
    float ly  = fy - (float)y0i;
    int   y1i = min(y0i + 1, H1 - 1);
    for (int i = 0; i < 38; ++i) {
      const int lin = i * 256 + t;
      const int cl = lin / 152, x = lin % 152;
      float fx = fminf(fmaxf(x * 0.5f - 0.25f, 0.f), (float)(W1 - 1));
      int   x0i = (int)floorf(fx);
      float lx  = fx - (float)x0i;
      int   x1i = min(x0i + 1, W1 - 1);
      const float* base = x1 + ((size_t)b * C + (c0l + cl)) * (H1 * W1);
      float a = base[y0i * W1 + x0i], bb = base[y0i * W1 + x1i];
      float c = base[y1i * W1 + x0i], d  = base[y1i * W1 + x1i];
      lds[cl][x] = (1.f - ly) * (a + lx * (bb - a)) + ly * (c + lx * (d - c));
    }
  } else {
    // 4x upsample of x2: src = (dst+0.5)*0.25 - 0.5, edge-clamped
    float fy = fminf(fmaxf((y + 0.5f) * 0.25f - 0.5f, 0.f), (float)(H2 - 1));
    int   y0i = (int)floorf(fy);
    float ly  = fy - (float)y0i;
    int   y1i = min(y0i + 1, H2 - 1);
    for (int i = 0; i < 38; ++i) {
      const int lin = i * 256 + t;
      const int cl = lin / 152, x = lin % 152;
      float fx = fminf(fmaxf((x + 0.5f) * 0.25f - 0.5f, 0.f), (float)(W2 - 1));
      int   x0i = (int)floorf(fx);
      float lx  = fx - (float)x0i;
      int   x1i = min(x0i + 1, W2 - 1);
      const float* base = x2 + ((size_t)b * C + (c0l + cl)) * (H2 * W2);
      float a = base[y0i * W2 + x0i], bb = base[y0i * W2 + x1i];
      float c = base[y1i * W2 + x0i], d  = base[y1i * W2 + x1i];
      lds[cl][x] = (1.f - ly) * (a + lx * (bb - a)) + ly * (c + lx * (d - c));
    }
  }
  __syncthreads();
  const int cg = tile * 64;  // global fused-channel base
  // write phase: lin over 152 x * 16 channel-quads = 2432; 4 channels/lane
  for (int i = 0; i < 10; ++i) {
    const int lin = i * 256 + t;
    if (lin < 152 * 16) {
      const int x = lin >> 4, cq = lin & 15;
      T* p = feat + (((size_t)b * H0 + y) * W0 + x) * CT + cg + cq * 4;
      st4(p, lds[cq * 4 + 0][x], lds[cq * 4 + 1][x],
             lds[cq * 4 + 2][x], lds[cq * 4 + 3][x]);
    }
  }
}

// ---------------------------------------------------------------------------
// Kernel 2: RoIAlign from BHWC feat. Block = (k, cgroup); 768 blocks.
// Thread t owns channel cg*256+t for ALL 49 output cells of roi k ->
// full within-roi corner reuse (L1/L2), and the block's output region
// out[k, cg*256..+256, :, :] is a contiguous 50KB run.
// x-sample weights/offsets hoisted (14 samples, static unroll, no scratch).
// LDS [256][49] stage (stride 49 = 17 mod 32: conflict-free) -> float4 writes.
// ---------------------------------------------------------------------------
template <typename T>
__global__ __launch_bounds__(256) void roi_kernel(
    const T* __restrict__ feat, const float* __restrict__ boxes,
    const float* __restrict__ ratio, const float* __restrict__ offset,
    const float* __restrict__ shape, float* __restrict__ out) {
  __shared__ float lds[256 * 49];
  const int blk = blockIdx.x;
  const int cg  = blk % 3;
  const int k   = blk / 3;
  const int b   = k >> 7;      // N = 128
  const int t   = threadIdx.x;
  const int c   = cg * 256 + t;

  // scale factors (batch 0, per reference)
  const float padded_h = floorf(shape[0] * ratio[0] + 2.f * offset[0]);
  const float padded_w = floorf(shape[1] * ratio[1] + 2.f * offset[1]);
  const float sx = (float)W0 / padded_w;
  const float sy = (float)H0 / padded_h;
  // per-batch roi transform
  const float rHb = ratio[b * 2 + 0], rWb = ratio[b * 2 + 1];
  const float topb = offset[b * 2 + 0], leftb = offset[b * 2 + 1];
  const float* bx = boxes + (size_t)k * 4;
  const float x1s = (bx[0] * rWb + leftb) * sx;
  const float y1s = (bx[1] * rHb + topb) * sy;
  const float x2s = (bx[2] * rWb + leftb) * sx;
  const float y2s = (bx[3] * rHb + topb) * sy;
  const float bw = fmaxf(x2s - x1s, 1.f) / OUTS;
  const float bh = fmaxf(y2s - y1s, 1.f) / OUTS;

  // hoisted x-sample data: 14 samples, validity folded into weights
  float hx[14], lx[14];
  int xo0[14], xo1[14];
  #pragma unroll
  for (int s = 0; s < 14; ++s) {
    const float X = x1s + ((float)s * 0.5f + 0.25f) * bw;
    const bool vx = (X >= -1.f) && (X <= (float)W0);
    const float Xc = fminf(fmaxf(X, 0.f), (float)(W0 - 1));
    const float xf = floorf(Xc);
    const float l  = Xc - xf;
    const int x0i = (int)xf;
    const int x1i = min(x0i + 1, W0 - 1);
    hx[s]  = vx ? (1.f - l) : 0.f;
    lx[s]  = vx ? l : 0.f;
    xo0[s] = x0i * CT;
    xo1[s] = x1i * CT;
  }

  const T* fb = feat + (size_t)b * (H0 * W0 * CT) + c;

  for (int ph = 0; ph < OUTS; ++ph) {
    float acc[OUTS] = {0.f, 0.f, 0.f, 0.f, 0.f, 0.f, 0.f};
    #pragma unroll
    for (int iy = 0; iy < 2; ++iy) {
      const float Y = y1s + ((float)ph + (float)iy * 0.5f + 0.25f) * bh;
      const bool vy = (Y >= -1.f) && (Y <= (float)H0);
      const float Yc = fminf(fmaxf(Y, 0.f), (float)(H0 - 1));
      const float yf = floorf(Yc);
      const float ly = Yc - yf;
      const int y0i = (int)yf;
      const int y1i = min(y0i + 1, H0 - 1);
      const float w0 = vy ? (1.f - ly) * 0.25f : 0.f;  // fold mean /4 + vy
      const float w1 = vy ? ly * 0.25f : 0.f;
      const T* r0 = fb + (size_t)y0i * (W0 * CT);
      const T* r1 = fb + (size_t)y1i * (W0 * CT);
      #pragma unroll
      for (int pw = 0; pw < OUTS; ++pw) {
        #pragma unroll
        for (int ix = 0; ix < 2; ++ix) {
          const int s = pw * 2 + ix;
          const float a00 = ldf(r0 + xo0[s]);
          const float a01 = ldf(r0 + xo1[s]);
          const float a10 = ldf(r1 + xo0[s]);
          const float a11 = ldf(r1 + xo1[s]);
          acc[pw] += w0 * (hx[s] * a00 + lx[s] * a01) +
                     w1 * (hx[s] * a10 + lx[s] * a11);
        }
      }
    }
    #pragma unroll
    for (int pw = 0; pw < OUTS; ++pw) lds[t * 49 + ph * 7 + pw] = acc[pw];
  }
  __syncthreads();
  // contiguous 50176B block write: 12544 floats = 3136 float4
  float* ob = out + (size_t)k * (CT * 49) + (size_t)cg * (256 * 49);
  const float4* ls = reinterpret_cast<const float4*>(lds);
  float4* os = reinterpret_cast<float4*>(ob);
  for (int i = 0; i < 13; ++i) {
    const int idx = i * 256 + t;
    if (idx < 3136) os[idx] = ls[idx];
  }
}

extern "C" void kernel_launch(void* const* d_in, const int* in_sizes, int n_in,
                              void* d_out, int out_size, void* d_ws, size_t ws_size,
                              hipStream_t stream) {
  const float* x0     = (const float*)d_in[0];
  const float* x1     = (const float*)d_in[1];
  const float* x2     = (const float*)d_in[2];
  const float* boxes  = (const float*)d_in[3];
  const float* ratio  = (const float*)d_in[4];
  const float* offset = (const float*)d_in[5];
  const float* shape  = (const float*)d_in[6];
  float* out = (float*)d_out;

  const size_t feat_elems = (size_t)B * H0 * W0 * CT;  // 23,347,200
  const dim3 g1(B * H0 * 12), blk(256);
  const dim3 g2(K * 3);

  if (ws_size >= feat_elems * sizeof(float)) {
    float* feat = (float*)d_ws;
    fuse_kernel<float><<<g1, blk, 0, stream>>>(x0, x1, x2, feat);
    roi_kernel<float><<<g2, blk, 0, stream>>>(feat, boxes, ratio, offset, shape, out);
  } else {
    __hip_bfloat16* feat = (__hip_bfloat16*)d_ws;
    fuse_kernel<__hip_bfloat16><<<g1, blk, 0, stream>>>(x0, x1, x2, feat);
    roi_kernel<__hip_bfloat16><<<g2, blk, 0, stream>>>(feat, boxes, ratio, offset, shape, out);
  }
}

// Round 4
// 139.346 us; speedup vs baseline: 1.3939x; 1.2017x over previous
//
#include <hip/hip_runtime.h>
#include <hip/hip_bf16.h>

// Problem constants (fixed by setup_inputs)
constexpr int B  = 2;
constexpr int C  = 256;       // channels per level
constexpr int H0 = 100, W0 = 152;
constexpr int H1 = 50,  W1 = 76;
constexpr int H2 = 25,  W2 = 38;
constexpr int N  = 128;       // rois per batch
constexpr int K  = B * N;     // 256 rois
constexpr int CT = 3 * C;     // 768 fused channels
constexpr int OUTS = 7;       // output grid

#define DEV __device__ __forceinline__

DEV float ldbf(const __hip_bfloat16* p) { return __bfloat162float(*p); }

// pack 4 channels -> 8B store
DEV void st4bf(__hip_bfloat16* p, float a, float b, float c, float d) {
  union { __hip_bfloat16 h[4]; uint2 u; } pk;
  pk.h[0] = __float2bfloat16(a); pk.h[1] = __float2bfloat16(b);
  pk.h[2] = __float2bfloat16(c); pk.h[3] = __float2bfloat16(d);
  *reinterpret_cast<uint2*>(p) = pk.u;
}

// ---------------------------------------------------------------------------
// Kernel 1: fused upsample + concat + NCHW->BHWC transpose, bf16 feat.
// Block = (b, y, tile); tile in [0,12): level = tile>>2, 64-channel slice.
// Level 0: float4-coalesced transpose via LDS [64][153].
// Levels 1/2 (separable upsample): load the two source rows coalesced
// (float4 / float2), fuse the y-lerp into an LDS row buffer
// ([64][81] / [64][39], row-step-4 access = 2 lanes/bank = free), then the
// write phase only x-lerps from LDS. Writes are 4-channel packed bf16 (8B).
// ---------------------------------------------------------------------------
__global__ __launch_bounds__(256) void fuse_kernel(
    const float* __restrict__ x0, const float* __restrict__ x1,
    const float* __restrict__ x2, __hip_bfloat16* __restrict__ feat) {
  __shared__ float buf[64 * 153];   // 39.2 KB (level 0 worst case)
  const int blk  = blockIdx.x;
  const int tile = blk % 12;
  const int by   = blk / 12;
  const int y    = by % H0;
  const int b    = by / H0;
  const int t    = threadIdx.x;
  const int level = tile >> 2;          // 0: x0 copy, 1: up(x1), 2: up(x2)
  const int c0l   = (tile & 3) * 64;    // channel base within level

  __hip_bfloat16* const orow =
      feat + (((size_t)b * H0 + y) * W0) * CT + tile * 64;

  if (level == 0) {
    // ---- pure transpose: 64 ch x 38 float4 coalesced loads ----
    const float* src = x0 + (((size_t)b * C + c0l) * H0 + y) * W0;
    for (int i = 0; i < 10; ++i) {
      const int lin = i * 256 + t;
      if (lin < 2432) {
        const int cl = lin / 38, xq = lin % 38;
        const float4 v =
            *reinterpret_cast<const float4*>(src + (size_t)cl * (H0 * W0) + xq * 4);
        float* d = &buf[cl * 153 + xq * 4];
        d[0] = v.x; d[1] = v.y; d[2] = v.z; d[3] = v.w;
      }
    }
    __syncthreads();
    for (int i = 0; i < 10; ++i) {
      const int lin = i * 256 + t;
      if (lin < 2432) {
        const int x = lin >> 4, cq = lin & 15;
        st4bf(orow + (size_t)x * CT + cq * 4,
              buf[(cq * 4 + 0) * 153 + x], buf[(cq * 4 + 1) * 153 + x],
              buf[(cq * 4 + 2) * 153 + x], buf[(cq * 4 + 3) * 153 + x]);
      }
    }
  } else if (level == 1) {
    // ---- 2x upsample: src = (dst+0.5)*0.5 - 0.5, edge-clamped ----
    const float fy = fminf(fmaxf(y * 0.5f - 0.25f, 0.f), (float)(H1 - 1));
    const int   y0i = (int)fy;
    const float ly  = fy - (float)y0i;
    const int   y1i = min(y0i + 1, H1 - 1);
    const int rstep = (y1i - y0i) * W1;
    const float* s0 = x1 + (((size_t)b * C + c0l) * H1 + y0i) * W1;
    // 64 ch x 19 float4 = 1216 units; fuse y-lerp into LDS row buffer
    for (int i = 0; i < 5; ++i) {
      const int lin = i * 256 + t;
      if (lin < 1216) {
        const int cl = lin / 19, xq = lin % 19;
        const float* p = s0 + (size_t)cl * (H1 * W1) + xq * 4;
        const float4 v0 = *reinterpret_cast<const float4*>(p);
        const float4 v1 = *reinterpret_cast<const float4*>(p + rstep);
        float* d = &buf[cl * 81 + xq * 4];
        d[0] = v0.x + ly * (v1.x - v0.x);
        d[1] = v0.y + ly * (v1.y - v0.y);
        d[2] = v0.z + ly * (v1.z - v0.z);
        d[3] = v0.w + ly * (v1.w - v0.w);
      }
    }
    __syncthreads();
    for (int i = 0; i < 10; ++i) {
      const int lin = i * 256 + t;
      if (lin < 2432) {
        const int x = lin >> 4, cq = lin & 15;
        const float fx = fminf(fmaxf(x * 0.5f - 0.25f, 0.f), (float)(W1 - 1));
        const int   x0i = (int)fx;
        const float lx  = fx - (float)x0i;
        const int   x1i = min(x0i + 1, W1 - 1);
        const float* r = &buf[cq * 4 * 81];
        float v[4];
        #pragma unroll
        for (int j = 0; j < 4; ++j) {
          const float a = r[j * 81 + x0i], bb = r[j * 81 + x1i];
          v[j] = a + lx * (bb - a);
        }
        st4bf(orow + (size_t)x * CT + cq * 4, v[0], v[1], v[2], v[3]);
      }
    }
  } else {
    // ---- 4x upsample: src = (dst+0.5)*0.25 - 0.5, edge-clamped ----
    const float fy = fminf(fmaxf(y * 0.25f - 0.375f, 0.f), (float)(H2 - 1));
    const int   y0i = (int)fy;
    const float ly  = fy - (float)y0i;
    const int   y1i = min(y0i + 1, H2 - 1);
    const int rstep = (y1i - y0i) * W2;
    const float* s0 = x2 + (((size_t)b * C + c0l) * H2 + y0i) * W2;
    // 64 ch x 19 float2 = 1216 units (W2=38 rows are only 8B-aligned)
    for (int i = 0; i < 5; ++i) {
      const int lin = i * 256 + t;
      if (lin < 1216) {
        const int cl = lin / 19, xq = lin % 19;
        const float* p = s0 + (size_t)cl * (H2 * W2) + xq * 2;
        const float2 v0 = *reinterpret_cast<const float2*>(p);
        const float2 v1 = *reinterpret_cast<const float2*>(p + rstep);
        float* d = &buf[cl * 39 + xq * 2];
        d[0] = v0.x + ly * (v1.x - v0.x);
        d[1] = v0.y + ly * (v1.y - v0.y);
      }
    }
    __syncthreads();
    for (int i = 0; i < 10; ++i) {
      const int lin = i * 256 + t;
      if (lin < 2432) {
        const int x = lin >> 4, cq = lin & 15;
        const float fx = fminf(fmaxf(x * 0.25f - 0.375f, 0.f), (float)(W2 - 1));
        const int   x0i = (int)fx;
        const float lx  = fx - (float)x0i;
        const int   x1i = min(x0i + 1, W2 - 1);
        const float* r = &buf[cq * 4 * 39];
        float v[4];
        #pragma unroll
        for (int j = 0; j < 4; ++j) {
          const float a = r[j * 39 + x0i], bb = r[j * 39 + x1i];
          v[j] = a + lx * (bb - a);
        }
        st4bf(orow + (size_t)x * CT + cq * 4, v[0], v[1], v[2], v[3]);
      }
    }
  }
}

// ---------------------------------------------------------------------------
// Kernel 2: RoIAlign from bf16 BHWC feat. Block = (k, cgroup); 768 blocks.
// Thread t owns channel cg*256+t for ALL 49 output cells of roi k ->
// full within-roi corner reuse (L1/L2); block output region is a contiguous
// 50KB run. x-sample weights/offsets hoisted (14 samples, static unroll).
// LDS [256][49] stage (49 = 17 mod 32: conflict-free) -> float4 writes.
// 3 blocks/CU (150KB LDS) = exact grid/CU fit.
// ---------------------------------------------------------------------------
__global__ __launch_bounds__(256) void roi_kernel(
    const __hip_bfloat16* __restrict__ feat, const float* __restrict__ boxes,
    const float* __restrict__ ratio, const float* __restrict__ offset,
    const float* __restrict__ shape, float* __restrict__ out) {
  __shared__ float lds[256 * 49];
  const int blk = blockIdx.x;
  const int cg  = blk % 3;
  const int k   = blk / 3;
  const int b   = k >> 7;      // N = 128
  const int t   = threadIdx.x;
  const int c   = cg * 256 + t;

  // scale factors (batch 0, per reference)
  const float padded_h = floorf(shape[0] * ratio[0] + 2.f * offset[0]);
  const float padded_w = floorf(shape[1] * ratio[1] + 2.f * offset[1]);
  const float sx = (float)W0 / padded_w;
  const float sy = (float)H0 / padded_h;
  // per-batch roi transform
  const float rHb = ratio[b * 2 + 0], rWb = ratio[b * 2 + 1];
  const float topb = offset[b * 2 + 0], leftb = offset[b * 2 + 1];
  const float* bx = boxes + (size_t)k * 4;
  const float x1s = (bx[0] * rWb + leftb) * sx;
  const float y1s = (bx[1] * rHb + topb) * sy;
  const float x2s = (bx[2] * rWb + leftb) * sx;
  const float y2s = (bx[3] * rHb + topb) * sy;
  const float bw = fmaxf(x2s - x1s, 1.f) / OUTS;
  const float bh = fmaxf(y2s - y1s, 1.f) / OUTS;

  // hoisted x-sample data: 14 samples, validity folded into weights
  float hx[14], lx[14];
  int xo0[14], xo1[14];
  #pragma unroll
  for (int s = 0; s < 14; ++s) {
    const float X = x1s + ((float)s * 0.5f + 0.25f) * bw;
    const bool vx = (X >= -1.f) && (X <= (float)W0);
    const float Xc = fminf(fmaxf(X, 0.f), (float)(W0 - 1));
    const float xf = floorf(Xc);
    const float l  = Xc - xf;
    const int x0i = (int)xf;
    const int x1i = min(x0i + 1, W0 - 1);
    hx[s]  = vx ? (1.f - l) : 0.f;
    lx[s]  = vx ? l : 0.f;
    xo0[s] = x0i * CT;
    xo1[s] = x1i * CT;
  }

  const __hip_bfloat16* fb = feat + (size_t)b * (H0 * W0 * CT) + c;

  for (int ph = 0; ph < OUTS; ++ph) {
    float acc[OUTS] = {0.f, 0.f, 0.f, 0.f, 0.f, 0.f, 0.f};
    #pragma unroll
    for (int iy = 0; iy < 2; ++iy) {
      const float Y = y1s + ((float)ph + (float)iy * 0.5f + 0.25f) * bh;
      const bool vy = (Y >= -1.f) && (Y <= (float)H0);
      const float Yc = fminf(fmaxf(Y, 0.f), (float)(H0 - 1));
      const float yf = floorf(Yc);
      const float ly = Yc - yf;
      const int y0i = (int)yf;
      const int y1i = min(y0i + 1, H0 - 1);
      const float w0 = vy ? (1.f - ly) * 0.25f : 0.f;  // fold mean /4 + vy
      const float w1 = vy ? ly * 0.25f : 0.f;
      const __hip_bfloat16* r0 = fb + (size_t)y0i * (W0 * CT);
      const __hip_bfloat16* r1 = fb + (size_t)y1i * (W0 * CT);
      #pragma unroll
      for (int pw = 0; pw < OUTS; ++pw) {
        #pragma unroll
        for (int ix = 0; ix < 2; ++ix) {
          const int s = pw * 2 + ix;
          const float a00 = ldbf(r0 + xo0[s]);
          const float a01 = ldbf(r0 + xo1[s]);
          const float a10 = ldbf(r1 + xo0[s]);
          const float a11 = ldbf(r1 + xo1[s]);
          acc[pw] += w0 * (hx[s] * a00 + lx[s] * a01) +
                     w1 * (hx[s] * a10 + lx[s] * a11);
        }
      }
    }
    #pragma unroll
    for (int pw = 0; pw < OUTS; ++pw) lds[t * 49 + ph * 7 + pw] = acc[pw];
  }
  __syncthreads();
  // contiguous 50176B block write: 12544 floats = 3136 float4
  float* ob = out + (size_t)k * (CT * 49) + (size_t)cg * (256 * 49);
  const float4* ls = reinterpret_cast<const float4*>(lds);
  float4* os = reinterpret_cast<float4*>(ob);
  for (int i = 0; i < 13; ++i) {
    const int idx = i * 256 + t;
    if (idx < 3136) os[idx] = ls[idx];
  }
}

extern "C" void kernel_launch(void* const* d_in, const int* in_sizes, int n_in,
                              void* d_out, int out_size, void* d_ws, size_t ws_size,
                              hipStream_t stream) {
  const float* x0     = (const float*)d_in[0];
  const float* x1     = (const float*)d_in[1];
  const float* x2     = (const float*)d_in[2];
  const float* boxes  = (const float*)d_in[3];
  const float* ratio  = (const float*)d_in[4];
  const float* offset = (const float*)d_in[5];
  const float* shape  = (const float*)d_in[6];
  float* out = (float*)d_out;

  __hip_bfloat16* feat = (__hip_bfloat16*)d_ws;  // 46.7 MB, fits ws
  const dim3 blk(256);
  const dim3 g1(B * H0 * 12);
  const dim3 g2(K * 3);

  fuse_kernel<<<g1, blk, 0, stream>>>(x0, x1, x2, feat);
  roi_kernel<<<g2, blk, 0, stream>>>(feat, boxes, ratio, offset, shape, out);
}